// Round 7
// baseline (326.730 us; speedup 1.0000x reference)
//
#include <hip/hip_runtime.h>
#include <math.h>

// SplineConv x2 (K=4, dim=1, degree=1, mean aggr) + ELU + log_softmax.
// R7: agg1 was L2-miss bound (104MB FETCH, ~50% hit on 12.8MB table over
// 4MB/XCD L2s; more MLP didn't help in R6). Fix: channel-shard the gather
// tables so each XCD's working set fits its L2:
//   layer1: [quarter][node][4k][8ch] bf16 -> 64B/node/quarter, 3.2MB/quarter;
//           blockIdx&3 = quarter, round-robin XCD mapping pins 1 quarter/XCD.
//   layer2: same with 2 halves (channels padded to 16; pads never read back).
// spk re-read per shard via nontemporal loads (don't evict the table).
// Payload = (src*4+k0)|qf<<18: gather addr = one shl-add; v1 at +16B with a
// guard row (k0==3 impossible: u in [0,1)). Wave = 8 edge-slots x 8 ch.
// log_softmax in a separate tiny kernel (halves are in different blocks).

#define F_IN   48
#define HID    32
#define NCLS   10
#define KS     4
#define BKT_SH 8               // 256 nodes per bucket
#define TILE   4096            // edges per bucket_scatter block

__device__ inline unsigned short f2bf(float f) {
    unsigned x = __float_as_uint(f);
    unsigned r = x + 0x7FFFu + ((x >> 16) & 1u);  // RNE
    return (unsigned short)(r >> 16);
}
__device__ inline float bf2f(unsigned short u) {
    return __uint_as_float(((unsigned)u) << 16);
}

// ---------- CSR build ----------

__global__ void bucket_hist_kernel(const int* __restrict__ ei, int* __restrict__ bcnt,
                                   int E, int NB) {
    __shared__ int lcnt[256];
    int t = threadIdx.x;
    lcnt[t] = 0;
    __syncthreads();
    int e0 = blockIdx.x * TILE;
    int n = min(TILE, E - e0);
    for (int r = 0; r < TILE / 256; ++r) {
        int i = r * 256 + t;
        if (i < n) atomicAdd(&lcnt[ei[E + e0 + i] >> BKT_SH], 1);
    }
    __syncthreads();
    if (t < NB && lcnt[t] > 0) atomicAdd(&bcnt[t], lcnt[t]);
}

__global__ void mini_scan_kernel(const int* __restrict__ bcnt, int* __restrict__ bbase,
                                 int* __restrict__ gcur, int NB) {
    __shared__ int a[256], c[256];
    int t = threadIdx.x;
    int v = (t < NB) ? bcnt[t] : 0;
    a[t] = v; c[t] = v;
    __syncthreads();
    for (int o = 1; o < 256; o <<= 1) {
        int w = (t >= o) ? a[t - o] : 0;
        __syncthreads();
        a[t] += w;
        __syncthreads();
    }
    int ex = a[t] - c[t];
    if (t < NB) { bbase[t] = ex; gcur[t] = ex; }
    if (t == 0) bbase[NB] = a[255];
}

__global__ void bucket_scatter_kernel(const int* __restrict__ ei, const float* __restrict__ ea,
                                      int* __restrict__ gcur, uint2* __restrict__ tpd,
                                      int E, int NB) {
    __shared__ unsigned spl[TILE];
    __shared__ unsigned short sdst[TILE];
    __shared__ unsigned short inv[TILE];
    __shared__ int lcnt[256], loff[256], lrank[256], gb[256];
    int t = threadIdx.x;
    lcnt[t] = 0; lrank[t] = 0;
    __syncthreads();
    int e0 = blockIdx.x * TILE;
    int n = min(TILE, E - e0);
    for (int r = 0; r < TILE / 256; ++r) {
        int i = r * 256 + t;
        if (i < n) {
            int e = e0 + i;
            int src = ei[e];
            int dst = ei[E + e];
            float u = ea[e];
            float v = u * (float)(KS - 1);
            float vf = floorf(v);
            int k0 = min(max((int)vf, 0), KS - 1);
            unsigned qf = (unsigned)((v - vf) * 16383.f + 0.5f);  // 14-bit frac
            spl[i] = ((unsigned)src << 2) | (unsigned)k0 | (qf << 18);  // srck | frac
            sdst[i] = (unsigned short)dst;
            atomicAdd(&lcnt[dst >> BKT_SH], 1);
        }
    }
    __syncthreads();
    loff[t] = lcnt[t];
    __syncthreads();
    for (int o = 1; o < 256; o <<= 1) {
        int w = (t >= o) ? loff[t - o] : 0;
        __syncthreads();
        loff[t] += w;
        __syncthreads();
    }
    int ex = loff[t] - lcnt[t];
    __syncthreads();
    loff[t] = ex;
    if (t < NB) gb[t] = atomicAdd(&gcur[t], lcnt[t]);
    __syncthreads();
    for (int r = 0; r < TILE / 256; ++r) {
        int i = r * 256 + t;
        if (i < n) {
            int b = sdst[i] >> BKT_SH;
            int p = loff[b] + atomicAdd(&lrank[b], 1);
            inv[p] = (unsigned short)i;
        }
    }
    __syncthreads();
    for (int r = 0; r < TILE / 256; ++r) {
        int j = r * 256 + t;
        if (j < n) {
            int i = inv[j];
            int d = sdst[i];
            int b = d >> BKT_SH;
            int pos = gb[b] + (j - loff[b]);
            tpd[pos] = make_uint2(spl[i], (unsigned)d);
        }
    }
}

__global__ void node_sort_kernel(const uint2* __restrict__ tpd, const int* __restrict__ bbase,
                                 unsigned* __restrict__ spk, int* __restrict__ offs,
                                 int N, int NB) {
    __shared__ int hc[256], hs[256], hr[256];
    int b = blockIdx.x;
    int t = threadIdx.x;
    int nb0 = b << BKT_SH;
    int nb = min(256, N - nb0);
    int base = bbase[b];
    int m = bbase[b + 1] - base;
    hc[t] = 0; hr[t] = 0;
    __syncthreads();
    for (int i = t; i < m; i += 256) atomicAdd(&hc[tpd[base + i].y - nb0], 1);
    __syncthreads();
    hs[t] = hc[t];
    __syncthreads();
    for (int o = 1; o < 256; o <<= 1) {
        int w = (t >= o) ? hs[t - o] : 0;
        __syncthreads();
        hs[t] += w;
        __syncthreads();
    }
    if (t < nb) offs[nb0 + t] = base + (hs[t] - hc[t]);
    if (b == NB - 1 && t == 0) offs[N] = base + m;
    for (int i = t; i < m; i += 256) {
        uint2 rec = tpd[base + i];
        int d = rec.y - nb0;
        int p = (hs[d] - hc[d]) + atomicAdd(&hr[d], 1);
        spk[base + p] = rec.x;
    }
}

// ---------- xw tables (LDS-staged W; sharded output layouts) ----------

// qsk = (N+1)*32 ushorts per quarter; qsf = N*8 floats per quarter.
__global__ __launch_bounds__(320) void xw1_kernel(
        const float* __restrict__ X, const float* __restrict__ W,
        const float* __restrict__ R, unsigned short* __restrict__ outk,
        float* __restrict__ outr, int n, int qsk, int qsf) {
    __shared__ float lw[48 * 160];
    int t = threadIdx.x;
    for (int i = t; i < 48 * 160; i += 320) {
        int f = i / 160;
        int col = i - f * 160;
        lw[i] = (col < 128) ? W[(size_t)(col >> 5) * (48 * 32) + f * 32 + (col & 31)]
                            : R[f * 32 + (col - 128)];
    }
    __syncthreads();
    int g = t % 40;      // colgroup (4 cols)
    int lp = t / 40;     // local pair 0..7
    int n0 = (blockIdx.x * 8 + lp) * 2;
    if (n0 + 1 >= n) return;
    const float4* X0 = (const float4*)(X + (size_t)n0 * F_IN);
    const float4* X1 = (const float4*)(X + (size_t)(n0 + 1) * F_IN);
    float4 x0[12], x1[12];
#pragma unroll
    for (int i = 0; i < 12; ++i) { x0[i] = X0[i]; x1[i] = X1[i]; }
    const float4* lw4 = (const float4*)lw;  // lw4[f*40 + g]
    float4 a0 = {0,0,0,0}, a1 = {0,0,0,0};
#pragma unroll
    for (int fb = 0; fb < 12; ++fb) {
        float4 v0 = x0[fb], v1 = x1[fb];
#pragma unroll
        for (int j = 0; j < 4; ++j) {
            float s0 = (j == 0) ? v0.x : (j == 1) ? v0.y : (j == 2) ? v0.z : v0.w;
            float s1 = (j == 0) ? v1.x : (j == 1) ? v1.y : (j == 2) ? v1.z : v1.w;
            float4 w = lw4[(fb * 4 + j) * 40 + g];
            a0.x = fmaf(s0, w.x, a0.x); a0.y = fmaf(s0, w.y, a0.y);
            a0.z = fmaf(s0, w.z, a0.z); a0.w = fmaf(s0, w.w, a0.w);
            a1.x = fmaf(s1, w.x, a1.x); a1.y = fmaf(s1, w.y, a1.y);
            a1.z = fmaf(s1, w.z, a1.z); a1.w = fmaf(s1, w.w, a1.w);
        }
    }
    if (g < 32) {  // table col = k*32 + c; shard: [q][node][k][8c]
        int k = g >> 3;
        int c0 = (g & 7) * 4;
        int q = c0 >> 3;
        int coff = c0 & 7;
        uint2 u0, u1;
        u0.x = f2bf(a0.x) | ((unsigned)f2bf(a0.y) << 16);
        u0.y = f2bf(a0.z) | ((unsigned)f2bf(a0.w) << 16);
        u1.x = f2bf(a1.x) | ((unsigned)f2bf(a1.y) << 16);
        u1.y = f2bf(a1.z) | ((unsigned)f2bf(a1.w) << 16);
        size_t bi = (size_t)q * qsk + (size_t)k * 8 + coff;
        *(uint2*)(outk + bi + (size_t)n0 * 32) = u0;
        *(uint2*)(outk + bi + (size_t)(n0 + 1) * 32) = u1;
    } else {       // root: shard [q][node][8c]
        int o = (g - 32) * 4;
        int q = o >> 3;
        int coff = o & 7;
        size_t bi = (size_t)q * qsf + coff;
        *(float4*)(outr + bi + (size_t)n0 * 8) = a0;
        *(float4*)(outr + bi + (size_t)(n0 + 1) * 8) = a1;
    }
}

// h input is quartered [q][node][8c]; outputs sharded in 2 halves.
__global__ void xw2_kernel(const float* __restrict__ H, const float* __restrict__ W,
                           const float* __restrict__ R, unsigned short* __restrict__ outk,
                           float* __restrict__ outr, int n, int hqs, int qsk, int qsf) {
    __shared__ float lw2[32 * 50];
    int t = threadIdx.x;
    for (int i = t; i < 32 * 50; i += 256) {
        int f = i / 50;
        int col = i - f * 50;
        lw2[i] = (col < 40) ? W[(size_t)(col / 10) * (32 * 10) + f * 10 + (col % 10)]
                            : R[f * 10 + (col - 40)];
    }
    __syncthreads();
    int total = (n / 2) * 25;
    int id = blockIdx.x * blockDim.x + t;
    if (id >= total) return;
    int p = id % 25;
    int pr = id / 25;
    int n0 = 2 * pr;
    float4 h0[8], h1[8];
#pragma unroll
    for (int qq = 0; qq < 4; ++qq) {
        const float4* Hq0 = (const float4*)(H + (size_t)qq * hqs + (size_t)n0 * 8);
        const float4* Hq1 = (const float4*)(H + (size_t)qq * hqs + (size_t)(n0 + 1) * 8);
        h0[qq * 2] = Hq0[0]; h0[qq * 2 + 1] = Hq0[1];
        h1[qq * 2] = Hq1[0]; h1[qq * 2 + 1] = Hq1[1];
    }
    const float2* lwp = (const float2*)lw2;  // lwp[f*25 + p]
    float ax0 = 0.f, ay0 = 0.f, ax1 = 0.f, ay1 = 0.f;
#pragma unroll
    for (int fb = 0; fb < 8; ++fb) {
        float4 v0 = h0[fb], v1 = h1[fb];
#pragma unroll
        for (int j = 0; j < 4; ++j) {
            float s0 = (j == 0) ? v0.x : (j == 1) ? v0.y : (j == 2) ? v0.z : v0.w;
            float s1 = (j == 0) ? v1.x : (j == 1) ? v1.y : (j == 2) ? v1.z : v1.w;
            float2 w = lwp[(fb * 4 + j) * 25 + p];
            ax0 = fmaf(s0, w.x, ax0); ay0 = fmaf(s0, w.y, ay0);
            ax1 = fmaf(s1, w.x, ax1); ay1 = fmaf(s1, w.y, ay1);
        }
    }
    int col = 2 * p;
    if (col < 40) {           // col = k*10 + o; shard [hf][node][k][8c]
        int k = col / 10;
        int o = col - k * 10;
        int hf = o >> 3;
        int coff = o & 7;     // even; pairs never straddle the 8-boundary
        size_t bi = (size_t)hf * qsk + (size_t)k * 8 + coff;
        *(unsigned*)(outk + bi + (size_t)n0 * 32) =
            f2bf(ax0) | ((unsigned)f2bf(ay0) << 16);
        *(unsigned*)(outk + bi + (size_t)(n0 + 1) * 32) =
            f2bf(ax1) | ((unsigned)f2bf(ay1) << 16);
    } else {                  // root: shard [hf][node][8c]
        int o = col - 40;
        int hf = o >> 3;
        int coff = o & 7;
        size_t bi = (size_t)hf * qsf + coff;
        *(float2*)(outr + bi + (size_t)n0 * 8) = make_float2(ax0, ay0);
        *(float2*)(outr + bi + (size_t)(n0 + 1) * 8) = make_float2(ax1, ay1);
    }
}

// ---------- aggregation (channel-sharded, L2-resident tables) ----------

// tbl pre-offset by +c; payload p = srck | qf<<18; row = srck*16B, v1 at +16B.
__device__ inline float gath(const unsigned short* __restrict__ tbl, unsigned p) {
    unsigned sk = p & 0x3FFFFu;
    float fr = (float)(p >> 18) * (1.f / 16383.f);
    float v0 = bf2f(tbl[sk * 8]);
    float v1 = bf2f(tbl[sk * 8 + 8]);
    return fmaf(fr, v1 - v0, v0);
}

// Wave = 8 edge-slots x 8 channels; quarter = blockIdx&3 (XCD-pinned via %8
// round-robin). Block = 4 waves = 4 consecutive nodes, one quarter.
__global__ void agg1_kernel(const unsigned short* __restrict__ xwk,
                            const float* __restrict__ xroot,
                            const int* __restrict__ offs, const unsigned* __restrict__ spk,
                            const float* __restrict__ bias, float* __restrict__ h,
                            int n, int qsk, int qsf) {
    int lane = threadIdx.x & 63;
    int slot = lane >> 3;
    int c = lane & 7;
    int q = blockIdx.x & 3;
    int node = (blockIdx.x >> 2) * 4 + (threadIdx.x >> 6);
    if (node >= n) return;
    const unsigned short* tbl = xwk + (size_t)q * qsk + c;
    int beg = offs[node], end = offs[node + 1];
    float s0 = 0.f, s1 = 0.f;
    int e = beg + slot;
    for (; e + 8 < end; e += 16) {
        unsigned p0 = __builtin_nontemporal_load(spk + e);
        unsigned p1 = __builtin_nontemporal_load(spk + e + 8);
        s0 += gath(tbl, p0);
        s1 += gath(tbl, p1);
    }
    if (e < end) s0 += gath(tbl, __builtin_nontemporal_load(spk + e));
    float sum = s0 + s1;
    sum += __shfl_xor(sum, 8, 64);
    sum += __shfl_xor(sum, 16, 64);
    sum += __shfl_xor(sum, 32, 64);
    if (slot == 0) {
        int deg = end - beg;
        float m = sum / (float)(deg > 0 ? deg : 1);
        size_t idx = (size_t)q * qsf + (size_t)node * 8 + c;
        float o = m + xroot[idx] + bias[q * 8 + c];
        h[idx] = (o > 0.f) ? o : expm1f(o);
    }
}

// Same structure, 2 halves; writes raw logits (softmax needs both halves).
__global__ void agg2_kernel(const unsigned short* __restrict__ xwk,
                            const float* __restrict__ xroot,
                            const int* __restrict__ offs, const unsigned* __restrict__ spk,
                            const float* __restrict__ bias, float* __restrict__ lg,
                            int n, int qsk, int qsf) {
    int lane = threadIdx.x & 63;
    int slot = lane >> 3;
    int c = lane & 7;
    int hf = blockIdx.x & 1;
    int node = (blockIdx.x >> 1) * 4 + (threadIdx.x >> 6);
    if (node >= n) return;
    const unsigned short* tbl = xwk + (size_t)hf * qsk + c;
    int beg = offs[node], end = offs[node + 1];
    float s0 = 0.f, s1 = 0.f;
    int e = beg + slot;
    for (; e + 8 < end; e += 16) {
        unsigned p0 = __builtin_nontemporal_load(spk + e);
        unsigned p1 = __builtin_nontemporal_load(spk + e + 8);
        s0 += gath(tbl, p0);
        s1 += gath(tbl, p1);
    }
    if (e < end) s0 += gath(tbl, __builtin_nontemporal_load(spk + e));
    float sum = s0 + s1;
    sum += __shfl_xor(sum, 8, 64);
    sum += __shfl_xor(sum, 16, 64);
    sum += __shfl_xor(sum, 32, 64);
    if (slot == 0) {
        int deg = end - beg;
        float m = sum / (float)(deg > 0 ? deg : 1);
        size_t idx = (size_t)hf * qsf + (size_t)node * 8 + c;
        int ch = hf * 8 + c;
        lg[idx] = m + xroot[idx] + bias[min(ch, NCLS - 1)];  // pad ch garbage, ignored
    }
}

__global__ void softmax_kernel(const float* __restrict__ lg, float* __restrict__ out,
                               int n, int qsf) {
    int i = blockIdx.x * 256 + threadIdx.x;
    if (i >= n) return;
    const float* l0 = lg + (size_t)i * 8;
    float4 a = *(const float4*)l0;
    float4 b = *(const float4*)(l0 + 4);
    float2 cp = *(const float2*)(lg + (size_t)qsf + (size_t)i * 8);
    float v[10] = {a.x, a.y, a.z, a.w, b.x, b.y, b.z, b.w, cp.x, cp.y};
    float mx = v[0];
#pragma unroll
    for (int j = 1; j < 10; ++j) mx = fmaxf(mx, v[j]);
    float s = 0.f;
#pragma unroll
    for (int j = 0; j < 10; ++j) s += expf(v[j] - mx);
    float ls = logf(s) + mx;
    float* o = out + (size_t)i * 10;
#pragma unroll
    for (int j = 0; j < 10; ++j) o[j] = v[j] - ls;
}

extern "C" void kernel_launch(void* const* d_in, const int* in_sizes, int n_in,
                              void* d_out, int out_size, void* d_ws, size_t ws_size,
                              hipStream_t stream) {
    const float* x       = (const float*)d_in[0];
    const int*   ei      = (const int*)d_in[1];
    const float* ea      = (const float*)d_in[2];
    const float* W1      = (const float*)d_in[3];
    const float* root1   = (const float*)d_in[4];
    const float* bias1   = (const float*)d_in[5];
    const float* W2      = (const float*)d_in[6];
    const float* root2   = (const float*)d_in[7];
    const float* bias2   = (const float*)d_in[8];
    float* out = (float*)d_out;

    const int N = in_sizes[0] / F_IN;      // 50000
    const int E = in_sizes[2];             // 1600000
    const int NB = (N + 255) >> BKT_SH;    // 196
    const int QSK = (N + 1) * 32;          // ushorts per table shard (+guard row)
    const int QSF = N * 8;                 // floats per root/h/logit shard

    char* base = (char*)d_ws;
    size_t off = 0;
    auto alloc = [&](size_t bytes) {
        char* p = base + off;
        off = (off + bytes + 255) & ~(size_t)255;
        return (void*)p;
    };
    unsigned short* xwk1 = (unsigned short*)alloc((size_t)4 * QSK * 2);  // 12.8 MB
    float* xr1           = (float*)alloc((size_t)4 * QSF * 4);           // 6.4 MB
    float* h             = (float*)alloc((size_t)4 * QSF * 4);           // 6.4 MB
    int* offs            = (int*)alloc(((size_t)N + 1) * 4);
    int* bcnt            = (int*)alloc((size_t)NB * 4);
    int* bbase           = (int*)alloc(((size_t)NB + 1) * 4);
    int* gcur            = (int*)alloc((size_t)NB * 4);
    unsigned* spk        = (unsigned*)alloc((size_t)E * 4);              // 6.4 MB
    uint2* tpd           = (uint2*)xwk1;   // E*8 <= 4*QSK*2 (dead before xw1)
    unsigned short* xwk2 = xwk1;           // 2*QSK ushorts, aliases layer-1
    float* xr2           = xr1;            // 2*QSF floats
    float* lg            = h;              // logits alias h (h dead after xw2)
    if (ws_size < off) return;

    int ebk = (E + TILE - 1) / TILE;

    hipMemsetAsync(bcnt, 0, (size_t)NB * 4, stream);
    bucket_hist_kernel<<<ebk, 256, 0, stream>>>(ei, bcnt, E, NB);
    mini_scan_kernel<<<1, 256, 0, stream>>>(bcnt, bbase, gcur, NB);
    bucket_scatter_kernel<<<ebk, 256, 0, stream>>>(ei, ea, gcur, tpd, E, NB);
    node_sort_kernel<<<NB, 256, 0, stream>>>(tpd, bbase, spk, offs, N, NB);
    // xw1 after node_sort (tpd aliases xwk1)
    xw1_kernel<<<(N + 15) / 16, 320, 0, stream>>>(x, W1, root1, xwk1, xr1, N, QSK, QSF);
    agg1_kernel<<<((N + 3) / 4) * 4, 256, 0, stream>>>(xwk1, xr1, offs, spk, bias1, h,
                                                       N, QSK, QSF);
    {
        int total = (N / 2) * 25;
        xw2_kernel<<<(total + 255) / 256, 256, 0, stream>>>(h, W2, root2, xwk2, xr2,
                                                            N, QSF, QSK, QSF);
    }
    agg2_kernel<<<((N + 3) / 4) * 2, 256, 0, stream>>>(xwk2, xr2, offs, spk, bias2, lg,
                                                       N, QSK, QSF);
    softmax_kernel<<<(N + 255) / 256, 256, 0, stream>>>(lg, out, N, QSF);
}